// Round 1
// baseline (256.233 us; speedup 1.0000x reference)
//
#include <hip/hip_runtime.h>

// IRFDeconv3D: out[b,p,t] = sum_{tau<=t} data[b,p,tau] * knorm[b,t-tau]
// == per-batch GEMM A[16384x256] @ Toeplitz(knorm)[256x256], keep n<256.
//
// Kernel 1 (build_W): normalize irf, build transposed slab-major Toeplitz
//   W[b][kk][n][kl] (bf16) = knorm[n - (32*kk+kl)] if n >= k else 0
//   -> GEMM B-staging becomes a contiguous 16 KiB copy per K-step.
// Kernel 2 (conv_gemm): 64-pixel M-tiles, 4 waves, mfma_f32_16x16x32_bf16,
//   triangular skip of all-zero n-tiles (j < 2*kk).

typedef __attribute__((ext_vector_type(8))) short short8;
typedef __attribute__((ext_vector_type(4))) float floatx4;

#define T_BINS 256
#define PIX_PER_B (128 * 128)

__device__ inline unsigned short f2bf(float f) {
    unsigned int u = __float_as_uint(f);
    u += 0x7fffu + ((u >> 16) & 1u);   // round-to-nearest-even
    return (unsigned short)(u >> 16);
}

__global__ __launch_bounds__(256) void build_W(const float* __restrict__ irf,
                                               unsigned short* __restrict__ W) {
    __shared__ float red[256];
    __shared__ float knorm[256];
    const int b = blockIdx.x;
    const int t = threadIdx.x;
    float v = irf[b * T_BINS + t];
    red[t] = v;
    __syncthreads();
    for (int s = 128; s > 0; s >>= 1) {
        if (t < s) red[t] = fmaxf(red[t], red[t + s]);
        __syncthreads();
    }
    knorm[t] = v / red[0];
    __syncthreads();
    unsigned short* Wb = W + b * 65536;
    // 65536 elements per batch; e = (kk*256 + n)*32 + kl
    for (int i = 0; i < 256; i++) {
        int e = i * 256 + t;           // coalesced
        int kk = e >> 13;
        int rem = e & 8191;
        int n = rem >> 5;
        int kl = rem & 31;
        int k = kk * 32 + kl;
        Wb[e] = (n >= k) ? f2bf(knorm[n - k]) : (unsigned short)0;
    }
}

__global__ __launch_bounds__(256) void conv_gemm(const float* __restrict__ data,
                                                 const unsigned short* __restrict__ W,
                                                 float* __restrict__ out) {
    __shared__ __align__(16) unsigned short Alds[64 * 32];    // 4 KiB
    __shared__ __align__(16) unsigned short Blds[256 * 32];   // 16 KiB

    const int b = blockIdx.x >> 8;        // 256 m-tiles per batch
    const int mt = blockIdx.x & 255;
    const int pix0 = mt * 64;
    const int t = threadIdx.x;
    const int w = t >> 6;                 // wave id (0..3)
    const int l = t & 63;                 // lane
    const int lq = l >> 4;                // quad (0..3)
    const int lm = l & 15;

    const float* Ab = data + (size_t)(b * PIX_PER_B + pix0) * T_BINS;
    const unsigned short* Wb = W + b * 65536;

    floatx4 acc[16];
#pragma unroll
    for (int j = 0; j < 16; j++) acc[j] = (floatx4){0.f, 0.f, 0.f, 0.f};

    for (int kk = 0; kk < 8; kk++) {
        // --- stage A: 64 rows x 32 fp32 -> bf16 in LDS ---
#pragma unroll
        for (int i = 0; i < 2; i++) {
            int seg = t + 256 * i;        // 512 x 16B-src segments
            int row = seg >> 3;
            int c4 = seg & 7;
            const float4 v = *(const float4*)(Ab + (size_t)row * T_BINS + kk * 32 + c4 * 4);
            ushort4 p;
            p.x = f2bf(v.x); p.y = f2bf(v.y); p.z = f2bf(v.z); p.w = f2bf(v.w);
            *(ushort4*)(Alds + seg * 4) = p;
        }
        // --- stage B: contiguous 16 KiB slab copy ---
        const uint4* gB = (const uint4*)(Wb + kk * 8192);
        uint4* lB = (uint4*)Blds;
#pragma unroll
        for (int i = 0; i < 4; i++) {
            int seg = t + 256 * i;
            lB[seg] = gB[seg];
        }
        __syncthreads();

        // A-frag: A[m = lm][k = lq*8 + j], contiguous 8 bf16 = 16 B
        short8 a = *(const short8*)(Alds + (16 * w + lm) * 32 + lq * 8);
#pragma unroll
        for (int j = 0; j < 16; j++) {
            if (j >= 2 * kk) {  // n-tiles with n_max < k_min are all-zero
                short8 bf = *(const short8*)(Blds + (16 * j + lm) * 32 + lq * 8);
                acc[j] = __builtin_amdgcn_mfma_f32_16x16x32_bf16(a, bf, acc[j], 0, 0, 0);
            }
        }
        __syncthreads();
    }

    // epilogue: C/D layout col = lm, row = lq*4 + r
    float* Ob = out + (size_t)(b * PIX_PER_B + pix0 + 16 * w) * T_BINS;
#pragma unroll
    for (int j = 0; j < 16; j++) {
#pragma unroll
        for (int r = 0; r < 4; r++) {
            Ob[(size_t)(lq * 4 + r) * T_BINS + 16 * j + lm] = acc[j][r];
        }
    }
}

extern "C" void kernel_launch(void* const* d_in, const int* in_sizes, int n_in,
                              void* d_out, int out_size, void* d_ws, size_t ws_size,
                              hipStream_t stream) {
    const float* data = (const float*)d_in[0];   // [8,128,128,256,1] fp32
    const float* irf  = (const float*)d_in[1];   // [8,1,1,256,1] fp32
    float* outp = (float*)d_out;                 // [8,128,128,256,1] fp32
    unsigned short* W = (unsigned short*)d_ws;   // 8*8*256*32 bf16 = 1 MiB

    build_W<<<8, 256, 0, stream>>>(irf, W);
    conv_gemm<<<2048, 256, 0, stream>>>(data, W, outp);
}

// Round 2
// 250.757 us; speedup vs baseline: 1.0218x; 1.0218x over previous
//
#include <hip/hip_runtime.h>

// IRFDeconv3D: out[b,p,t] = sum_{tau<=t} data[b,p,tau] * knorm[b,t-tau]
// == per-batch GEMM A[16384x256] @ Toeplitz(knorm)[256x256], keep n<256.
//
// v2: barrier-free, LDS-free conv_gemm. Each wave owns 16 pixels (the MFMA
// A-fragment rows m=lane&15 are distinct per wave), loads A fragments
// directly from global (32B/lane contiguous), converts fp32->bf16 in-reg,
// and reads B fragments from the slab-major Toeplitz W (1 MiB, L2-resident;
// 1 KiB contiguous per wave B-load). Fully unrolled K-loop, triangular skip
// (n-tile j < 2*kk is all-zero) resolved at compile time. build_W widened
// to 256 blocks (round-1's 8-block version underused the GPU).

typedef __attribute__((ext_vector_type(8))) short short8;
typedef __attribute__((ext_vector_type(4))) float floatx4;

#define T_BINS 256
#define PIX_PER_B (128 * 128)

__device__ inline unsigned short f2bf(float f) {
    unsigned int u = __float_as_uint(f);
    u += 0x7fffu + ((u >> 16) & 1u);   // round-to-nearest-even
    return (unsigned short)(u >> 16);
}

// W[b][kk][n][kl] (bf16) = knorm[n - (32*kk+kl)] if n >= k else 0
// grid: 8 batches x 32 chunks; each block fills 2048 elements.
__global__ __launch_bounds__(256) void build_W(const float* __restrict__ irf,
                                               unsigned short* __restrict__ W) {
    __shared__ float red[256];
    __shared__ float knorm[256];
    const int b = blockIdx.x >> 5;
    const int z = blockIdx.x & 31;
    const int t = threadIdx.x;
    float v = irf[b * T_BINS + t];
    red[t] = v;
    __syncthreads();
    for (int s = 128; s > 0; s >>= 1) {
        if (t < s) red[t] = fmaxf(red[t], red[t + s]);
        __syncthreads();
    }
    knorm[t] = v / red[0];
    __syncthreads();
    unsigned short* Wb = W + b * 65536;
#pragma unroll
    for (int i = 0; i < 8; i++) {
        int e = z * 2048 + i * 256 + t;   // coalesced
        int kk = e >> 13;
        int n = (e >> 5) & 255;
        int kl = e & 31;
        int k = kk * 32 + kl;
        Wb[e] = (n >= k) ? f2bf(knorm[n - k]) : (unsigned short)0;
    }
}

__global__ __launch_bounds__(256) void conv_gemm(const float* __restrict__ data,
                                                 const unsigned short* __restrict__ W,
                                                 float* __restrict__ out) {
    const int b = blockIdx.x >> 8;        // 256 m-tiles per batch
    const int mt = blockIdx.x & 255;
    const int t = threadIdx.x;
    const int w = t >> 6;                 // wave id (0..3); waves independent
    const int l = t & 63;
    const int lq = l >> 4;                // quad (0..3)
    const int lm = l & 15;

    const int row = mt * 64 + w * 16 + lm;            // this lane's A row
    const float* Arow = data + ((size_t)b * PIX_PER_B + row) * T_BINS;
    const unsigned short* Wb = W + b * 65536;

    floatx4 acc[16];
#pragma unroll
    for (int j = 0; j < 16; j++) acc[j] = (floatx4){0.f, 0.f, 0.f, 0.f};

#pragma unroll
    for (int kk = 0; kk < 8; kk++) {
        // A-frag: A[m=lm][k=kk*32+lq*8 .. +7], 32B contiguous per lane
        const float4 va = *(const float4*)(Arow + kk * 32 + lq * 8);
        const float4 vb = *(const float4*)(Arow + kk * 32 + lq * 8 + 4);
        short8 a;
        a[0] = (short)f2bf(va.x); a[1] = (short)f2bf(va.y);
        a[2] = (short)f2bf(va.z); a[3] = (short)f2bf(va.w);
        a[4] = (short)f2bf(vb.x); a[5] = (short)f2bf(vb.y);
        a[6] = (short)f2bf(vb.z); a[7] = (short)f2bf(vb.w);
#pragma unroll
        for (int j = 0; j < 16; j++) {
            if (j >= 2 * kk) {  // compile-time after unroll: skip all-zero tiles
                short8 bf = *(const short8*)(Wb + kk * 8192 + (16 * j + lm) * 32 + lq * 8);
                acc[j] = __builtin_amdgcn_mfma_f32_16x16x32_bf16(a, bf, acc[j], 0, 0, 0);
            }
        }
    }

    // epilogue: C/D layout col = lm, row = lq*4 + r
    float* Ob = out + ((size_t)b * PIX_PER_B + mt * 64 + w * 16) * T_BINS;
#pragma unroll
    for (int j = 0; j < 16; j++) {
#pragma unroll
        for (int r = 0; r < 4; r++) {
            Ob[(size_t)(lq * 4 + r) * T_BINS + 16 * j + lm] = acc[j][r];
        }
    }
}

extern "C" void kernel_launch(void* const* d_in, const int* in_sizes, int n_in,
                              void* d_out, int out_size, void* d_ws, size_t ws_size,
                              hipStream_t stream) {
    const float* data = (const float*)d_in[0];   // [8,128,128,256,1] fp32
    const float* irf  = (const float*)d_in[1];   // [8,1,1,256,1] fp32
    float* outp = (float*)d_out;                 // [8,128,128,256,1] fp32
    unsigned short* W = (unsigned short*)d_ws;   // 8*8*256*32 bf16 = 1 MiB

    build_W<<<256, 256, 0, stream>>>(irf, W);
    conv_gemm<<<2048, 256, 0, stream>>>(data, W, outp);
}